// Round 5
// baseline (134.733 us; speedup 1.0000x reference)
//
#include <hip/hip_runtime.h>
#include <cstddef>

// Problem constants (fixed by the reference): B=4096, T=204800, D=32, H=64
#define DICE_EPS 1e-10f

typedef __attribute__((ext_vector_type(8))) short bf16x8;  // MFMA A/B frag
typedef __attribute__((ext_vector_type(4))) float f32x4;   // MFMA C/D frag

// Truncating fp32 -> (hi, lo) bf16 split: x ≈ hi + lo with |err| ~ 2^-17 |x|.
__device__ inline void f2bf_split(float x, short& hi, short& lo) {
  const unsigned u = __float_as_uint(x);
  hi = (short)(u >> 16);
  const float rem = x - __uint_as_float(u & 0xffff0000u);  // exact
  lo = (short)(__float_as_uint(rem) >> 16);
}

// ---------------------------------------------------------------------------
// Kernel 0: segment starts from sorted row_ids. seg[r] = first t with
// row_ids[t] >= r; seg[B] = T.
// ---------------------------------------------------------------------------
__global__ __launch_bounds__(256) void seg_starts(const int* __restrict__ row_ids,
                                                  int* __restrict__ seg, int T, int B) {
  const int t = blockIdx.x * 256 + threadIdx.x;
  if (t >= T) return;
  const int b = row_ids[t];
  const int a = (t == 0) ? 0 : row_ids[t - 1];
  if (t == 0) seg[0] = 0;
  for (int r = a + 1; r <= b; r++) seg[r] = t;
  if (t == T - 1)
    for (int r = b + 1; r <= B; r++) seg[r] = T;
}

// ---------------------------------------------------------------------------
// Kernel 1: MFMA GEMM  M_all[r][(i,k)] = cand[r][:] @ W1o[:][(i,k)] + W1b[i][k]
// (contraction over j=32; output cols flattened col = i*64 + k, 2048 wide).
// Output written as bf16 hi/lo planes in the attention B-frag layout:
//   Mhi[((r*4 + n)*64 + lane)*8 + jj] = bf16hi(M[i=8*(lane>>4)+jj][k=16n+(lane&15)])
// Grid: (B/16)*4 blocks; wave q of 16 per candidate-group handles col-tiles
// np = 8q .. 8q+7.  3 MFMAs per tile (hi*hi, hi*lo, lo*hi).
// ---------------------------------------------------------------------------
__global__ __launch_bounds__(256) void precompute_Mfrag(
    const float* __restrict__ cand, const float* __restrict__ W1,
    unsigned short* __restrict__ Mhi, unsigned short* __restrict__ Mlo) {
  const int lane = threadIdx.x & 63;
  const int wv = threadIdx.x >> 6;
  const int r0 = (blockIdx.x >> 2) * 16;       // candidate group base
  const int q = (blockIdx.x & 3) * 4 + wv;     // wave id 0..15 within group
  const int c = lane & 15, g = lane >> 4;

  // A-frag: A[m=c][j=8g+jj] = cand[r0+c][8g+jj]  (hi/lo split)
  bf16x8 Ahi, Alo;
  {
    const f32x4* ap = reinterpret_cast<const f32x4*>(cand + (size_t)(r0 + c) * 32 + 8 * g);
    const f32x4 a0 = ap[0], a1 = ap[1];
    const float av[8] = {a0.x, a0.y, a0.z, a0.w, a1.x, a1.y, a1.z, a1.w};
#pragma unroll
    for (int j = 0; j < 8; j++) {
      short h, l;
      f2bf_split(av[j], h, l);
      Ahi[j] = h; Alo[j] = l;
    }
  }

#pragma unroll
  for (int m = 0; m < 8; m++) {
    const int np = 8 * q + m;           // col-tile 0..127
    const int i = np >> 2;              // 0..31
    const int k = 16 * (np & 3) + c;    // 0..63
    // B-frag: B[j=8g+jj][col=c] = W1[(64 + 32*i + 8g + jj)*64 + k]
    const float* bp = W1 + (size_t)(64 + 32 * i + 8 * g) * 64 + k;
    bf16x8 Bhi, Blo;
#pragma unroll
    for (int jj = 0; jj < 8; jj++) {
      short h, l;
      f2bf_split(bp[(size_t)jj * 64], h, l);
      Bhi[jj] = h; Blo[jj] = l;
    }
    f32x4 Cz = {0.f, 0.f, 0.f, 0.f};
    Cz = __builtin_amdgcn_mfma_f32_16x16x32_bf16(Alo, Bhi, Cz, 0, 0, 0);
    Cz = __builtin_amdgcn_mfma_f32_16x16x32_bf16(Ahi, Blo, Cz, 0, 0, 0);
    Cz = __builtin_amdgcn_mfma_f32_16x16x32_bf16(Ahi, Bhi, Cz, 0, 0, 0);
    const float bias = W1[(size_t)(32 + i) * 64 + k];  // W1b[i][k]

    // C row = 4g + p = candidate index within group.
    const int nn = np & 3;
    const int jj2 = (np >> 2) & 7;
    const int lp = ((np >> 5) << 4) + c;  // attention lane that consumes this
#pragma unroll
    for (int p = 0; p < 4; p++) {
      const float v = Cz[p] + bias;
      const size_t r = (size_t)(r0 + 4 * g + p);
      const size_t off = ((r * 4 + nn) * 64 + lp) * 8 + jj2;
      const unsigned u = __float_as_uint(v);
      Mhi[off] = (unsigned short)(u >> 16);
      const float rem = v - __uint_as_float(u & 0xffff0000u);
      Mlo[off] = (unsigned short)(__float_as_uint(rem) >> 16);
    }
  }
}

// ---------------------------------------------------------------------------
// Kernel 2: one WAVE per candidate; 16 rows per MFMA tile.
//   A = bv tile (16x32) hi/lo-split, B = M_r frags loaded directly (4 col-
//   tiles, hi/lo planes). C layout: col=lane&15, row=(lane>>4)*4+reg.
//   Dice stats: 4-stage butterflies within 16-lane groups (per 4 rows).
// ---------------------------------------------------------------------------
__global__ __launch_bounds__(256) void attention_mfma(
    const float* __restrict__ cand, const float* __restrict__ behavior,
    const float* __restrict__ W1, const float* __restrict__ b1,
    const float* __restrict__ alpha, const float* __restrict__ W2,
    const float* __restrict__ b2, const unsigned short* __restrict__ Mhi,
    const unsigned short* __restrict__ Mlo, const int* __restrict__ seg,
    float* __restrict__ out) {
  const int lane = threadIdx.x & 63;
  const int wid = threadIdx.x >> 6;
  const int r = blockIdx.x * 4 + wid;  // this wave's candidate
  const int c = lane & 15;             // col-in-tile (B/C) == row m (A)
  const int g = lane >> 4;             // 16-lane group

  __shared__ float wlds[4][16];  // per-wave w[row] broadcast buffer

  const int t0 = seg[r];
  const int t1 = seg[r + 1];

  // --- B fragments: direct coalesced frag-layout loads (4x dwordx4 each). ---
  bf16x8 Bhi[4], Blo[4];
  {
    const bf16x8* mh = reinterpret_cast<const bf16x8*>(Mhi) + (size_t)r * 4 * 64 + lane;
    const bf16x8* ml = reinterpret_cast<const bf16x8*>(Mlo) + (size_t)r * 4 * 64 + lane;
#pragma unroll
    for (int n = 0; n < 4; n++) {
      Bhi[n] = mh[(size_t)n * 64];
      Blo[n] = ml[(size_t)n * 64];
    }
  }

  // --- per-lane col constants for cols 16n+c ---
  float base_n[4], al_n[4], w2_n[4];
#pragma unroll
  for (int n = 0; n < 4; n++) {
    base_n[n] = b1[16 * n + c];
    al_n[n] = alpha[16 * n + c];
    w2_n[n] = W2[16 * n + c];
  }
  for (int d = 0; d < 32; d++) {
    const float cd = cand[(size_t)r * 32 + d];  // wave-uniform -> s_load
#pragma unroll
    for (int n = 0; n < 4; n++)
      base_n[n] = fmaf(cd, W1[(size_t)d * 64 + 16 * n + c], base_n[n]);
  }
  const float b2v = b2[0];

  float acc[8];
#pragma unroll
  for (int jj = 0; jj < 8; jj++) acc[jj] = 0.f;

  for (int tb = t0; tb < t1; tb += 16) {
    // A fragment: bv[tb+c][8g .. 8g+7] (rows >= t1 padded with 0).
    const int trow = tb + c;
    f32x4 a0 = {0.f, 0.f, 0.f, 0.f}, a1 = {0.f, 0.f, 0.f, 0.f};
    if (trow < t1) {
      const f32x4* bp =
          reinterpret_cast<const f32x4*>(behavior + (size_t)trow * 32 + 8 * g);
      a0 = bp[0];
      a1 = bp[1];
    }
    bf16x8 Ahi, Alo;
    {
      const float av[8] = {a0.x, a0.y, a0.z, a0.w, a1.x, a1.y, a1.z, a1.w};
#pragma unroll
      for (int j = 0; j < 8; j++) {
        short h, l;
        f2bf_split(av[j], h, l);
        Ahi[j] = h; Alo[j] = l;
      }
    }

    // C[n] = A*B[n] with hi/lo cross terms (lolo dropped).
    f32x4 C[4];
#pragma unroll
    for (int n = 0; n < 4; n++) {
      f32x4 cz = {0.f, 0.f, 0.f, 0.f};
      cz = __builtin_amdgcn_mfma_f32_16x16x32_bf16(Alo, Bhi[n], cz, 0, 0, 0);
      cz = __builtin_amdgcn_mfma_f32_16x16x32_bf16(Ahi, Blo[n], cz, 0, 0, 0);
      cz = __builtin_amdgcn_mfma_f32_16x16x32_bf16(Ahi, Bhi[n], cz, 0, 0, 0);
      C[n] = cz;
    }

    // h = C + base; raw moments per row (row = 4g+j).
    float hm[4][4];  // [reg j][tile n]
    float s[4], s2[4];
#pragma unroll
    for (int j = 0; j < 4; j++) {
      float ss = 0.f, qq = 0.f;
#pragma unroll
      for (int n = 0; n < 4; n++) {
        const float h = C[n][j] + base_n[n];
        hm[j][n] = h;
        ss += h;
        qq += h * h;
      }
      s[j] = ss;
      s2[j] = qq;
    }
#pragma unroll
    for (int off = 1; off < 16; off <<= 1) {
#pragma unroll
      for (int j = 0; j < 4; j++) {
        s[j] += __shfl_xor(s[j], off, 64);
        s2[j] += __shfl_xor(s2[j], off, 64);
      }
    }

    // Dice + H->1 projection partials.
    float wp[4];
#pragma unroll
    for (int j = 0; j < 4; j++) {
      const float mean = s[j] * (1.f / 64.f);
      const float var = fmaxf(s2[j] * (1.f / 64.f) - mean * mean, 0.f);
      const float stdv = sqrtf(var + DICE_EPS);
      const float inv = __builtin_amdgcn_rcpf(stdv + DICE_EPS);
      float w = 0.f;
#pragma unroll
      for (int n = 0; n < 4; n++) {
        const float h = hm[j][n];
        const float e = __expf((mean - h) * inv);
        const float p = __builtin_amdgcn_rcpf(1.f + e);
        const float hd = (al_n[n] + p * (1.f - al_n[n])) * h;
        w = fmaf(hd, w2_n[n], w);
      }
      wp[j] = w;
    }
#pragma unroll
    for (int off = 1; off < 16; off <<= 1) {
#pragma unroll
      for (int j = 0; j < 4; j++) wp[j] += __shfl_xor(wp[j], off, 64);
    }

    // Broadcast w[row] to the lane holding that row in the A layout (m = c).
    if (c == 0) wlds[wid][4 * g + 0] = wp[0] + b2v;
    if (c == 1) wlds[wid][4 * g + 1] = wp[1] + b2v;
    if (c == 2) wlds[wid][4 * g + 2] = wp[2] + b2v;
    if (c == 3) wlds[wid][4 * g + 3] = wp[3] + b2v;
    const float w = wlds[wid][c];  // same-wave LDS; compiler orders via lgkmcnt

    acc[0] = fmaf(a0.x, w, acc[0]);
    acc[1] = fmaf(a0.y, w, acc[1]);
    acc[2] = fmaf(a0.z, w, acc[2]);
    acc[3] = fmaf(a0.w, w, acc[3]);
    acc[4] = fmaf(a1.x, w, acc[4]);
    acc[5] = fmaf(a1.y, w, acc[5]);
    acc[6] = fmaf(a1.z, w, acc[6]);
    acc[7] = fmaf(a1.w, w, acc[7]);
  }

  // Sum over the 16 rows (lanes c=0..15 within the group), once per candidate.
#pragma unroll
  for (int off = 1; off < 16; off <<= 1) {
#pragma unroll
    for (int jj = 0; jj < 8; jj++) acc[jj] += __shfl_xor(acc[jj], off, 64);
  }
  if (c == 0) {  // lanes 0,16,32,48 -> d = 8g .. 8g+7
    f32x4 o0 = {acc[0], acc[1], acc[2], acc[3]};
    f32x4 o1 = {acc[4], acc[5], acc[6], acc[7]};
    f32x4* op = reinterpret_cast<f32x4*>(out + (size_t)r * 32 + 8 * g);
    op[0] = o0;
    op[1] = o1;
  }
}

// ---------------------------------------------------------------------------
extern "C" void kernel_launch(void* const* d_in, const int* in_sizes, int n_in,
                              void* d_out, int out_size, void* d_ws, size_t ws_size,
                              hipStream_t stream) {
  const float* cand     = (const float*)d_in[0];
  const float* behavior = (const float*)d_in[1];
  const int*   row_ids  = (const int*)d_in[2];
  const float* W1       = (const float*)d_in[3];
  const float* b1       = (const float*)d_in[4];
  const float* alpha    = (const float*)d_in[5];
  const float* W2       = (const float*)d_in[6];
  const float* b2       = (const float*)d_in[7];
  float* out = (float*)d_out;

  const int B = in_sizes[0] / 32;  // 4096
  const int T = in_sizes[2];       // 204800

  // ws layout: Mhi (B*2048 shorts = 16.8 MB), Mlo (16.8 MB), seg (B+1 ints)
  unsigned short* Mhi = (unsigned short*)d_ws;
  unsigned short* Mlo = Mhi + (size_t)B * 2048;
  int* seg = (int*)(Mlo + (size_t)B * 2048);

  seg_starts<<<(T + 255) / 256, 256, 0, stream>>>(row_ids, seg, T, B);
  precompute_Mfrag<<<(B / 16) * 4, 256, 0, stream>>>(cand, W1, Mhi, Mlo);
  attention_mfma<<<B / 4, 256, 0, stream>>>(cand, behavior, W1, b1, alpha, W2,
                                            b2, Mhi, Mlo, seg, out);
}

// Round 6
// 116.126 us; speedup vs baseline: 1.1602x; 1.1602x over previous
//
#include <hip/hip_runtime.h>
#include <cstddef>

// Problem constants (fixed by the reference): B=4096, T=204800, D=32, H=64
#define DICE_EPS 1e-10f

typedef __attribute__((ext_vector_type(8))) short bf16x8;  // MFMA A/B frag
typedef __attribute__((ext_vector_type(4))) float f32x4;   // MFMA C/D frag
typedef __attribute__((ext_vector_type(4))) unsigned int u32x4;

// Truncating fp32 -> (hi, lo) bf16 split: x ≈ hi + lo with |err| ~ 2^-17 |x|.
__device__ inline void f2bf_split(float x, short& hi, short& lo) {
  const unsigned u = __float_as_uint(x);
  hi = (short)(u >> 16);
  const float rem = x - __uint_as_float(u & 0xffff0000u);  // exact
  lo = (short)(__float_as_uint(rem) >> 16);
}

// ---------------------------------------------------------------------------
// Kernel 1 (fused): seg_starts + MFMA M-frag producer with LDS-bounced
// coalesced stores.
//   M_all[r][(i,k)] = cand[r][:] @ W1o[:][(i,k)] + W1b[i][k], written as bf16
//   hi/lo planes in the attention B-frag layout:
//     plane[((r*4 + nn)*64 + lane')*8 + jj2],  lane' = 16*(i>>3) + (k&15)
//   Grid: (B/16)*4 = 1024 blocks; block covers candidate group r0..r0+15 and
//   col-tile quarter z = blk&3 (tiles np = 32z .. 32z+31, 8 per wave).
//   R5's direct global scatter (2B stores, ~8x write amplification) is
//   replaced by: ds_write_b16 scatter into a 2x16 KB block image, barrier,
//   then 256B-contiguous uint4 copy-out (fully coalesced).
//   Blocks with blockIdx*256 < T also compute seg[] (free rider, no extra
//   dispatch): seg[r] = first t with row_ids[t] >= r; seg[B] = T.
// ---------------------------------------------------------------------------
__global__ __launch_bounds__(256) void precompute_Mfrag(
    const float* __restrict__ cand, const float* __restrict__ W1,
    const int* __restrict__ row_ids, unsigned short* __restrict__ Mhi,
    unsigned short* __restrict__ Mlo, int* __restrict__ seg, int T, int B) {
  // --- seg part (first ceil(T/256) blocks) ---
  {
    const int t = blockIdx.x * 256 + threadIdx.x;
    if (t < T) {
      const int b = row_ids[t];
      const int a = (t == 0) ? 0 : row_ids[t - 1];
      if (t == 0) seg[0] = 0;
      for (int r = a + 1; r <= b; r++) seg[r] = t;
      if (t == T - 1)
        for (int r = b + 1; r <= B; r++) seg[r] = T;
    }
  }

  // --- producer part ---
  const int lane = threadIdx.x & 63;
  const int wv = threadIdx.x >> 6;
  const int r0 = (blockIdx.x >> 2) * 16;    // candidate group base
  const int z = blockIdx.x & 3;             // col-tile quarter
  const int q = z * 4 + wv;                 // wave id 0..15 within group
  const int c = lane & 15, g = lane >> 4;

  // Block image: [plane][ (rr*4+nn)*16 + c ][ jj2 ] shorts = 2 x 16 KB.
  __shared__ __align__(16) unsigned short limg[2][16 * 4 * 16 * 8];

  // A-frag: A[m][j=8g+jj] = cand[r0+m][8g+jj], m = c  (hi/lo split)
  bf16x8 Ahi, Alo;
  {
    const f32x4* ap =
        reinterpret_cast<const f32x4*>(cand + (size_t)(r0 + c) * 32 + 8 * g);
    const f32x4 a0 = ap[0], a1 = ap[1];
    const float av[8] = {a0.x, a0.y, a0.z, a0.w, a1.x, a1.y, a1.z, a1.w};
#pragma unroll
    for (int j = 0; j < 8; j++) {
      short h, l;
      f2bf_split(av[j], h, l);
      Ahi[j] = h; Alo[j] = l;
    }
  }

#pragma unroll
  for (int m = 0; m < 8; m++) {
    const int np = 8 * q + m;           // col-tile 32z .. 32z+31
    const int i = np >> 2;              // 0..31
    const int k = 16 * (np & 3) + c;    // 0..63
    // B-frag: B[j=8g+jj][col=c] = W1[(64 + 32*i + 8g + jj)*64 + k]
    const float* bp = W1 + (size_t)(64 + 32 * i + 8 * g) * 64 + k;
    bf16x8 Bhi, Blo;
#pragma unroll
    for (int jj = 0; jj < 8; jj++) {
      short h, l;
      f2bf_split(bp[(size_t)jj * 64], h, l);
      Bhi[jj] = h; Blo[jj] = l;
    }
    f32x4 Cz = {0.f, 0.f, 0.f, 0.f};
    Cz = __builtin_amdgcn_mfma_f32_16x16x32_bf16(Alo, Bhi, Cz, 0, 0, 0);
    Cz = __builtin_amdgcn_mfma_f32_16x16x32_bf16(Ahi, Blo, Cz, 0, 0, 0);
    Cz = __builtin_amdgcn_mfma_f32_16x16x32_bf16(Ahi, Bhi, Cz, 0, 0, 0);
    const float bias = W1[(size_t)(32 + i) * 64 + k];  // W1b[i][k]

    const int nn = np & 3;
    const int jj2 = (np >> 2) & 7;
    // C layout: lane (c,g) reg p holds C[row=4g+p][col=c]; row = rr (cand).
#pragma unroll
    for (int p = 0; p < 4; p++) {
      const float v = Cz[p] + bias;
      const int rr = 4 * g + p;
      const int idx = ((rr * 4 + nn) * 16 + c) * 8 + jj2;
      short h, l;
      f2bf_split(v, h, l);
      limg[0][idx] = (unsigned short)h;
      limg[1][idx] = (unsigned short)l;
    }
  }
  __syncthreads();

  // Coalesced copy-out: 1024 uint4 per plane, 256B-contiguous runs.
  // src uint4 u holds chunk (rr*4+nn)=u>>4, sub=u&15 (sub*8 shorts within
  // the 128-short chunk). dst uint4 index = (r0*4 + (u>>4))*64 + z*16 + sub.
  {
    const u32x4* src_h = reinterpret_cast<const u32x4*>(limg[0]);
    const u32x4* src_l = reinterpret_cast<const u32x4*>(limg[1]);
    u32x4* dst_h = reinterpret_cast<u32x4*>(Mhi);
    u32x4* dst_l = reinterpret_cast<u32x4*>(Mlo);
#pragma unroll
    for (int it = 0; it < 4; it++) {
      const int u = it * 256 + threadIdx.x;
      const size_t dst = (size_t)(r0 * 4 + (u >> 4)) * 64 + z * 16 + (u & 15);
      dst_h[dst] = src_h[u];
      dst_l[dst] = src_l[u];
    }
  }
}

// ---------------------------------------------------------------------------
// Kernel 2: one WAVE per candidate; 16 rows per MFMA tile.
//   A = bv tile (16x32) hi/lo-split, B = M_r frags loaded directly (4 col-
//   tiles, hi/lo planes, coalesced dwordx4). C layout: col=lane&15,
//   row=(lane>>4)*4+reg. Dice stats: 4-stage butterflies per 16-lane group.
// ---------------------------------------------------------------------------
__global__ __launch_bounds__(256) void attention_mfma(
    const float* __restrict__ cand, const float* __restrict__ behavior,
    const float* __restrict__ W1, const float* __restrict__ b1,
    const float* __restrict__ alpha, const float* __restrict__ W2,
    const float* __restrict__ b2, const unsigned short* __restrict__ Mhi,
    const unsigned short* __restrict__ Mlo, const int* __restrict__ seg,
    float* __restrict__ out) {
  const int lane = threadIdx.x & 63;
  const int wid = threadIdx.x >> 6;
  const int r = blockIdx.x * 4 + wid;  // this wave's candidate
  const int c = lane & 15;             // col-in-tile (B/C) == row m (A)
  const int g = lane >> 4;             // 16-lane group

  __shared__ float wlds[4][16];  // per-wave w[row] broadcast buffer

  const int t0 = seg[r];
  const int t1 = seg[r + 1];

  // --- B fragments: direct coalesced frag-layout loads (4x dwordx4 each). ---
  bf16x8 Bhi[4], Blo[4];
  {
    const bf16x8* mh =
        reinterpret_cast<const bf16x8*>(Mhi) + (size_t)r * 4 * 64 + lane;
    const bf16x8* ml =
        reinterpret_cast<const bf16x8*>(Mlo) + (size_t)r * 4 * 64 + lane;
#pragma unroll
    for (int n = 0; n < 4; n++) {
      Bhi[n] = mh[(size_t)n * 64];
      Blo[n] = ml[(size_t)n * 64];
    }
  }

  // --- per-lane col constants for cols 16n+c ---
  float base_n[4], al_n[4], w2_n[4];
#pragma unroll
  for (int n = 0; n < 4; n++) {
    base_n[n] = b1[16 * n + c];
    al_n[n] = alpha[16 * n + c];
    w2_n[n] = W2[16 * n + c];
  }
  for (int d = 0; d < 32; d++) {
    const float cd = cand[(size_t)r * 32 + d];  // wave-uniform -> s_load
#pragma unroll
    for (int n = 0; n < 4; n++)
      base_n[n] = fmaf(cd, W1[(size_t)d * 64 + 16 * n + c], base_n[n]);
  }
  const float b2v = b2[0];

  float acc[8];
#pragma unroll
  for (int jj = 0; jj < 8; jj++) acc[jj] = 0.f;

  for (int tb = t0; tb < t1; tb += 16) {
    // A fragment: bv[tb+c][8g .. 8g+7] (rows >= t1 padded with 0).
    const int trow = tb + c;
    f32x4 a0 = {0.f, 0.f, 0.f, 0.f}, a1 = {0.f, 0.f, 0.f, 0.f};
    if (trow < t1) {
      const f32x4* bp =
          reinterpret_cast<const f32x4*>(behavior + (size_t)trow * 32 + 8 * g);
      a0 = bp[0];
      a1 = bp[1];
    }
    bf16x8 Ahi, Alo;
    {
      const float av[8] = {a0.x, a0.y, a0.z, a0.w, a1.x, a1.y, a1.z, a1.w};
#pragma unroll
      for (int j = 0; j < 8; j++) {
        short h, l;
        f2bf_split(av[j], h, l);
        Ahi[j] = h; Alo[j] = l;
      }
    }

    // C[n] = A*B[n] with hi/lo cross terms (lolo dropped).
    f32x4 C[4];
#pragma unroll
    for (int n = 0; n < 4; n++) {
      f32x4 cz = {0.f, 0.f, 0.f, 0.f};
      cz = __builtin_amdgcn_mfma_f32_16x16x32_bf16(Alo, Bhi[n], cz, 0, 0, 0);
      cz = __builtin_amdgcn_mfma_f32_16x16x32_bf16(Ahi, Blo[n], cz, 0, 0, 0);
      cz = __builtin_amdgcn_mfma_f32_16x16x32_bf16(Ahi, Bhi[n], cz, 0, 0, 0);
      C[n] = cz;
    }

    // h = C + base; raw moments per row (row = 4g+j).
    float hm[4][4];  // [reg j][tile n]
    float s[4], s2[4];
#pragma unroll
    for (int j = 0; j < 4; j++) {
      float ss = 0.f, qq = 0.f;
#pragma unroll
      for (int n = 0; n < 4; n++) {
        const float h = C[n][j] + base_n[n];
        hm[j][n] = h;
        ss += h;
        qq += h * h;
      }
      s[j] = ss;
      s2[j] = qq;
    }
#pragma unroll
    for (int off = 1; off < 16; off <<= 1) {
#pragma unroll
      for (int j = 0; j < 4; j++) {
        s[j] += __shfl_xor(s[j], off, 64);
        s2[j] += __shfl_xor(s2[j], off, 64);
      }
    }

    // Dice + H->1 projection partials.
    float wp[4];
#pragma unroll
    for (int j = 0; j < 4; j++) {
      const float mean = s[j] * (1.f / 64.f);
      const float var = fmaxf(s2[j] * (1.f / 64.f) - mean * mean, 0.f);
      const float stdv = sqrtf(var + DICE_EPS);
      const float inv = __builtin_amdgcn_rcpf(stdv + DICE_EPS);
      float w = 0.f;
#pragma unroll
      for (int n = 0; n < 4; n++) {
        const float h = hm[j][n];
        const float e = __expf((mean - h) * inv);
        const float p = __builtin_amdgcn_rcpf(1.f + e);
        const float hd = (al_n[n] + p * (1.f - al_n[n])) * h;
        w = fmaf(hd, w2_n[n], w);
      }
      wp[j] = w;
    }
#pragma unroll
    for (int off = 1; off < 16; off <<= 1) {
#pragma unroll
      for (int j = 0; j < 4; j++) wp[j] += __shfl_xor(wp[j], off, 64);
    }

    // Broadcast w[row] to the lane holding that row in the A layout (m = c).
    if (c == 0) wlds[wid][4 * g + 0] = wp[0] + b2v;
    if (c == 1) wlds[wid][4 * g + 1] = wp[1] + b2v;
    if (c == 2) wlds[wid][4 * g + 2] = wp[2] + b2v;
    if (c == 3) wlds[wid][4 * g + 3] = wp[3] + b2v;
    const float w = wlds[wid][c];  // same-wave LDS; compiler orders via lgkmcnt

    acc[0] = fmaf(a0.x, w, acc[0]);
    acc[1] = fmaf(a0.y, w, acc[1]);
    acc[2] = fmaf(a0.z, w, acc[2]);
    acc[3] = fmaf(a0.w, w, acc[3]);
    acc[4] = fmaf(a1.x, w, acc[4]);
    acc[5] = fmaf(a1.y, w, acc[5]);
    acc[6] = fmaf(a1.z, w, acc[6]);
    acc[7] = fmaf(a1.w, w, acc[7]);
  }

  // Sum over the 16 rows (lanes c=0..15 within the group), once per candidate.
#pragma unroll
  for (int off = 1; off < 16; off <<= 1) {
#pragma unroll
    for (int jj = 0; jj < 8; jj++) acc[jj] += __shfl_xor(acc[jj], off, 64);
  }
  if (c == 0) {  // lanes 0,16,32,48 -> d = 8g .. 8g+7
    f32x4 o0 = {acc[0], acc[1], acc[2], acc[3]};
    f32x4 o1 = {acc[4], acc[5], acc[6], acc[7]};
    f32x4* op = reinterpret_cast<f32x4*>(out + (size_t)r * 32 + 8 * g);
    op[0] = o0;
    op[1] = o1;
  }
}

// ---------------------------------------------------------------------------
extern "C" void kernel_launch(void* const* d_in, const int* in_sizes, int n_in,
                              void* d_out, int out_size, void* d_ws, size_t ws_size,
                              hipStream_t stream) {
  const float* cand     = (const float*)d_in[0];
  const float* behavior = (const float*)d_in[1];
  const int*   row_ids  = (const int*)d_in[2];
  const float* W1       = (const float*)d_in[3];
  const float* b1       = (const float*)d_in[4];
  const float* alpha    = (const float*)d_in[5];
  const float* W2       = (const float*)d_in[6];
  const float* b2       = (const float*)d_in[7];
  float* out = (float*)d_out;

  const int B = in_sizes[0] / 32;  // 4096
  const int T = in_sizes[2];       // 204800

  // ws layout: Mhi (B*2048 shorts = 16.8 MB), Mlo (16.8 MB), seg (B+1 ints)
  unsigned short* Mhi = (unsigned short*)d_ws;
  unsigned short* Mlo = Mhi + (size_t)B * 2048;
  int* seg = (int*)(Mlo + (size_t)B * 2048);

  // Grid must cover both the producer ((B/16)*4 blocks) and seg (T/256).
  const int nblk = max((B / 16) * 4, (T + 255) / 256);
  precompute_Mfrag<<<nblk, 256, 0, stream>>>(cand, W1, row_ids, Mhi, Mlo, seg,
                                             T, B);
  attention_mfma<<<B / 4, 256, 0, stream>>>(cand, behavior, W1, b1, alpha, W2,
                                            b2, Mhi, Mlo, seg, out);
}